// Round 5
// baseline (901.456 us; speedup 1.0000x reference)
//
#include <hip/hip_runtime.h>
#include <math.h>

// ---------------------------------------------------------------------------
// LocalSlidingWindow_DisentangledAttention — Round 5: 16-wave split-k attn.
// B=4, S=8192, H=768, NH=12, HD=64, BS=128, WIN=384, BUCKETS=256.
//
// attn: 1024 thr = 16 waves = (qw 0..7, kh 0..1). Wave owns q-strip of 16 and
// k-half of 192. Softmax/PV merged across kh pairs via small LDS buffers.
// 151.5 KB LDS, 1 block/CU but 16 waves resident (2x R4's 8).
// ---------------------------------------------------------------------------

#define NHEADS 12
#define HDIM   64
#define SEQ    8192
#define HID    768
#define BSZ    128
#define WIN    384
#define PBUCK  512

typedef __attribute__((ext_vector_type(8))) short bf16x8;
typedef __attribute__((ext_vector_type(4))) float f32x4;
#define MFMA16(a, b, c) __builtin_amdgcn_mfma_f32_16x16x32_bf16((a), (b), (c), 0, 0, 0)

// attn LDS byte map (dynamic, 151552 total)
#define SM_C2P 0        // [128][392] bf16 = 100352  (phase 1-2)
#define SM_K   0        // [384][64]  bf16 = 49152   (phase 4-5)
#define SM_O32 0        // [128][68]  f32  = 34816   (PV merge)
#define SM_PQ  49152    // [384][64]  bf16 = 49152   (phase 4)
#define SM_VT  49152    // [64][384]  bf16 = 49152   (PV)
#define SM_PKH 100352   // [384][64]  bf16 = 49152   (phase 1)
#define SM_TL  100352   // 2 x [32][184] bf16 = 23552 (phase 4)
#define SM_RED 124160   // m[256] + s[256] f32 = 2048 (softmax merge)
#define SM_LUT 149504   // [511] int = 2044
#define SMEM_ATTN 151552

#define SOFT_C 0.10411790f   // log2(e)/sqrt(192)

__device__ __forceinline__ unsigned short f2bf(float f) {
  unsigned int x = __builtin_bit_cast(unsigned int, f);
  unsigned int r = (x + 0x7FFFu + ((x >> 16) & 1u)) >> 16;
  return (unsigned short)r;
}
__device__ __forceinline__ float bf2f(unsigned short u) {
  unsigned int x = ((unsigned int)u) << 16;
  return __builtin_bit_cast(float, x);
}

// idx(rel) for rel in [-383, 127]
__device__ __forceinline__ int bucket_idx(int rel) {
  if (rel >= -128) return rel + 256;
  float a = (float)(-rel);
  float t = logf(a * (1.0f / 128.0f));
  t = t / 0.6892332813f;
  t = t * 127.0f;
  int lp = (int)(ceilf(t) + 128.0f);
  int r = 256 - lp;
  return r < 0 ? 0 : r;
}

// Fragment load from swizzled row-major bf16 LDS tile.
__device__ __forceinline__ bf16x8 ldfrag(const char* sm, int byteBase, int row,
                                         int rowBytes, int slice, int g) {
  const int swz = (row & 7) << 4;
  const char* p = sm + byteBase + row * rowBytes;
  union { bf16x8 v; uint2 u2[2]; } w;
  w.u2[0] = *(const uint2*)(p + (((slice << 6) + (g << 3)) ^ swz));
  w.u2[1] = *(const uint2*)(p + (((slice << 6) + 32 + (g << 3)) ^ swz));
  return w.v;
}

// ---------------------------------------------------------------------------
// Weight transpose fp32 -> bf16: Wt[z*768 + n][k] = W_z[k][n]
__global__ __launch_bounds__(256) void conv_wt(const float* __restrict__ W0,
                                               const float* __restrict__ W1,
                                               const float* __restrict__ W2,
                                               unsigned short* __restrict__ Wt) {
  __shared__ float tile[64][65];
  int bx = blockIdx.x, by = blockIdx.y, z = blockIdx.z;
  const float* W = (z == 0) ? W0 : (z == 1 ? W1 : W2);
  int t = threadIdx.x;
  int c = t & 63, r0 = (t >> 6) * 16;
#pragma unroll
  for (int rr = 0; rr < 16; ++rr)
    tile[r0 + rr][c] = W[(size_t)(by * 64 + r0 + rr) * HID + bx * 64 + c];
  __syncthreads();
#pragma unroll
  for (int rr = 0; rr < 16; ++rr) {
    int nw = r0 + rr;
    Wt[((size_t)z * HID + bx * 64 + nw) * HID + by * 64 + c] = f2bf(tile[c][nw]);
  }
}

// Positional projection (fp32 math) -> bf16 posq/posk [h][512][64]
__global__ __launch_bounds__(256) void pos_gemm(
    const float* __restrict__ relpos, const float* __restrict__ Wq,
    const float* __restrict__ Wk, const float* __restrict__ bq,
    const float* __restrict__ bk, unsigned short* __restrict__ posq,
    unsigned short* __restrict__ posk) {
  __shared__ float At[32][68];
  __shared__ float Bs[32][68];
  int m0 = blockIdx.x * 64;
  int n0 = blockIdx.y * 64;
  int w = n0 / HID;
  int nc0 = n0 % HID;
  const float* W = (w == 0) ? Wq : Wk;
  const float* bias = (w == 0) ? bq : bk;
  int t = threadIdx.x;
  int tx = t & 15, ty = t >> 4;
  float acc[4][4] = {};
  for (int k0 = 0; k0 < HID; k0 += 32) {
#pragma unroll
    for (int u = 0; u < 2; ++u) {
      int f = t * 2 + u;
      int r = f >> 3, c4 = f & 7;
      float4 av = *(const float4*)(relpos + (size_t)(m0 + r) * HID + k0 + c4 * 4);
      At[c4 * 4 + 0][r] = av.x; At[c4 * 4 + 1][r] = av.y;
      At[c4 * 4 + 2][r] = av.z; At[c4 * 4 + 3][r] = av.w;
    }
#pragma unroll
    for (int u = 0; u < 2; ++u) {
      int f = t * 2 + u;
      int kk = f >> 4, c4 = f & 15;
      float4 bv4 = *(const float4*)(W + (size_t)(k0 + kk) * HID + nc0 + c4 * 4);
      *(float4*)&Bs[kk][c4 * 4] = bv4;
    }
    __syncthreads();
#pragma unroll
    for (int kk = 0; kk < 32; ++kk) {
      float4 a4 = *(const float4*)&At[kk][ty * 4];
      float4 b4 = *(const float4*)&Bs[kk][tx * 4];
      float av[4] = {a4.x, a4.y, a4.z, a4.w};
      float bvv[4] = {b4.x, b4.y, b4.z, b4.w};
#pragma unroll
      for (int i = 0; i < 4; ++i)
#pragma unroll
        for (int jj = 0; jj < 4; ++jj) acc[i][jj] += av[i] * bvv[jj];
    }
    __syncthreads();
  }
  int h = nc0 >> 6;
  unsigned short* dst = (w == 0) ? posq : posk;
#pragma unroll
  for (int i = 0; i < 4; ++i) {
    int p = m0 + ty * 4 + i;
    ushort4 o;
    o.x = f2bf(acc[i][0] + bias[nc0 + tx * 4 + 0]);
    o.y = f2bf(acc[i][1] + bias[nc0 + tx * 4 + 1]);
    o.z = f2bf(acc[i][2] + bias[nc0 + tx * 4 + 2]);
    o.w = f2bf(acc[i][3] + bias[nc0 + tx * 4 + 3]);
    *(ushort4*)(dst + ((size_t)h * PBUCK + p) * HDIM + tx * 4) = o;
  }
}

// ---------------------------------------------------------------------------
// QKV projection, bf16 MFMA. Tile 128x128, BK=64, 256 thr = 4 waves (2x2).
__global__ __launch_bounds__(256) void qkv_mfma(
    const float* __restrict__ hidden, const unsigned short* __restrict__ Wt,
    const float* __restrict__ bq, const float* __restrict__ bk,
    const float* __restrict__ bv, unsigned short* __restrict__ qws,
    unsigned short* __restrict__ kws, unsigned short* __restrict__ vt) {
  __shared__ unsigned short As[8192];
  __shared__ unsigned short Bs[8192];
  const int t = threadIdx.x;
  const int lane = t & 63;
  const int l15 = lane & 15, g = lane >> 4;
  const int wave = t >> 6;
  const int wy = wave >> 1, wx = wave & 1;
  const int n0 = blockIdx.x * 128;
  const int m0 = blockIdx.y * 128;

  f32x4 acc[4][4];
#pragma unroll
  for (int i = 0; i < 4; ++i)
#pragma unroll
    for (int j = 0; j < 4; ++j) acc[i][j] = (f32x4){0.f, 0.f, 0.f, 0.f};

  for (int k0 = 0; k0 < HID; k0 += 64) {
#pragma unroll
    for (int i = 0; i < 4; ++i) {
      int c = t + i * 256;
      int row = c >> 3, cx = c & 7;
      const float4* src =
          (const float4*)(hidden + (size_t)(m0 + row) * HID + k0 + cx * 8);
      float4 a = src[0], b = src[1];
      union { bf16x8 v; unsigned short u[8]; } w;
      w.u[0] = f2bf(a.x); w.u[1] = f2bf(a.y); w.u[2] = f2bf(a.z); w.u[3] = f2bf(a.w);
      w.u[4] = f2bf(b.x); w.u[5] = f2bf(b.y); w.u[6] = f2bf(b.z); w.u[7] = f2bf(b.w);
      *(bf16x8*)((char*)As + row * 128 + ((cx * 16) ^ ((row & 7) << 4))) = w.v;
    }
#pragma unroll
    for (int i = 0; i < 4; ++i) {
      int c = t + i * 256;
      int row = c >> 3, cx = c & 7;
      uint4 v = *(const uint4*)(Wt + (size_t)(n0 + row) * HID + k0 + cx * 8);
      *(uint4*)((char*)Bs + row * 128 + ((cx * 16) ^ ((row & 7) << 4))) = v;
    }
    __syncthreads();
    bf16x8 af[4][2], bf[4][2];
#pragma unroll
    for (int mt = 0; mt < 4; ++mt) {
      int row = wy * 64 + mt * 16 + l15;
      const char* p = (const char*)As + row * 128;
      int swz = (row & 7) << 4;
#pragma unroll
      for (int s = 0; s < 2; ++s)
        af[mt][s] = *(const bf16x8*)(p + ((s * 64 + g * 16) ^ swz));
    }
#pragma unroll
    for (int nt = 0; nt < 4; ++nt) {
      int row = wx * 64 + nt * 16 + l15;
      const char* p = (const char*)Bs + row * 128;
      int swz = (row & 7) << 4;
#pragma unroll
      for (int s = 0; s < 2; ++s)
        bf[nt][s] = *(const bf16x8*)(p + ((s * 64 + g * 16) ^ swz));
    }
#pragma unroll
    for (int mt = 0; mt < 4; ++mt)
#pragma unroll
      for (int nt = 0; nt < 4; ++nt) {
        acc[mt][nt] = MFMA16(af[mt][0], bf[nt][0], acc[mt][nt]);
        acc[mt][nt] = MFMA16(af[mt][1], bf[nt][1], acc[mt][nt]);
      }
    __syncthreads();
  }

  const int w = n0 / HID;
  const float* bias = (w == 0) ? bq : (w == 1 ? bk : bv);
#pragma unroll
  for (int nt = 0; nt < 4; ++nt) {
    int gn = n0 + wx * 64 + nt * 16 + l15;
    int nc = gn - w * HID;
    int h = nc >> 6, d = nc & 63;
    float bval = bias[nc];
#pragma unroll
    for (int mt = 0; mt < 4; ++mt) {
      f32x4 a = acc[mt][nt];
#pragma unroll
      for (int r = 0; r < 4; ++r) {
        int m = m0 + wy * 64 + mt * 16 + 4 * g + r;
        int bl = m >> 13, s = m & 8191;
        size_t bh = (size_t)bl * NHEADS + h;
        unsigned short val = f2bf(a[r] + bval);
        if (w == 0)
          qws[(bh * SEQ + s) * HDIM + d] = val;
        else if (w == 1)
          kws[(bh * SEQ + s) * HDIM + d] = val;
        else
          vt[bh * ((size_t)HDIM * SEQ) + (size_t)d * SEQ + s] = val;
      }
    }
  }
}

// ---------------------------------------------------------------------------
// MFMA attention, 16 waves. wave = (qw = wave&7 -> q-strip, kh = wave>>3 ->
// k-half of 192). acc[12] f32x4: S[k = 192kh+16t+4g+r][q = 16qw+l15].
__global__ __launch_bounds__(1024) void attn_kernel(
    const unsigned short* __restrict__ qws, const unsigned short* __restrict__ kws,
    const unsigned short* __restrict__ vt, const unsigned short* __restrict__ posq,
    const unsigned short* __restrict__ posk, unsigned short* __restrict__ ctx) {
  extern __shared__ char smem[];
  int* iLUT = (int*)(smem + SM_LUT);

  const int tid = threadIdx.x;
  const int wave = tid >> 6;
  const int lane = tid & 63;
  const int l15 = lane & 15;
  const int g = lane >> 4;
  const int qw = wave & 7, kh = wave >> 3;
  const int qs = qw << 4;
  const int qg = qs + l15;           // this lane's softmax q row

  const int n = blockIdx.x & 63;
  const int bh = blockIdx.x >> 6;
  const int h = bh % NHEADS;
  const int b = bh / NHEADS;

  const unsigned short* kbh = kws + (size_t)bh * SEQ * HDIM;
  const unsigned short* vtbh = vt + (size_t)bh * ((size_t)HDIM * SEQ);
  const unsigned short* pqh = posq + (size_t)h * PBUCK * HDIM;
  const unsigned short* pkh = posk + (size_t)h * PBUCK * HDIM;

  // ---- phase 0: stage full posk [384][64], LUT; load Q fragments from global
  for (int idx = tid; idx < 384 * 8; idx += 1024) {
    int row = idx >> 3, c = idx & 7;
    uint4 v = *(const uint4*)(pkh + row * HDIM + c * 8);
    *(uint4*)(smem + SM_PKH + row * 128 + ((c * 16) ^ ((row & 7) << 4))) = v;
  }
  if (tid < 511) iLUT[tid] = bucket_idx(tid - 383);

  bf16x8 qf0, qf1;
  {
    const char* qrow =
        (const char*)(qws + ((size_t)bh * SEQ + n * BSZ + qs + l15) * HDIM);
    union { bf16x8 v; uint2 u2[2]; } u0, u1;
    u0.u2[0] = *(const uint2*)(qrow + g * 8);
    u0.u2[1] = *(const uint2*)(qrow + g * 8 + 32);
    u1.u2[0] = *(const uint2*)(qrow + 64 + g * 8);
    u1.u2[1] = *(const uint2*)(qrow + 96 + g * 8);
    qf0 = u0.v; qf1 = u1.v;
  }
  __syncthreads();  // B1

  // ---- phase 1: C2P[q][p] = Q . posk^T ; wave does q-strip qw x p-half kh
  unsigned short* C2P = (unsigned short*)(smem + SM_C2P);
  __builtin_amdgcn_s_setprio(1);
#pragma unroll
  for (int ntl = 0; ntl < 12; ++ntl) {
    int prow = 192 * kh + 16 * ntl + l15;
    bf16x8 b0 = ldfrag(smem, SM_PKH, prow, 128, 0, g);
    bf16x8 b1 = ldfrag(smem, SM_PKH, prow, 128, 1, g);
    f32x4 c = {0.f, 0.f, 0.f, 0.f};
    c = MFMA16(qf0, b0, c);
    c = MFMA16(qf1, b1, c);
#pragma unroll
    for (int r = 0; r < 4; ++r)
      C2P[(qs + 4 * g + r) * 392 + prow] = f2bf(c[r]);
  }
  __builtin_amdgcn_s_setprio(0);
  __syncthreads();  // B2

  // ---- phase 2: gather c2p into acc
  f32x4 acc[12];
#pragma unroll
  for (int t = 0; t < 12; ++t) acc[t] = (f32x4){0.f, 0.f, 0.f, 0.f};
  {
    const unsigned short* c2pRow = C2P + qg * 392;
#pragma unroll
    for (int t = 0; t < 12; ++t) {
#pragma unroll
      for (int r = 0; r < 4; ++r) {
        int k = 192 * kh + 16 * t + 4 * g + r;
        int idxv = iLUT[qg - k + 383];
        acc[t][r] += bf2f(c2pRow[idxv]);
      }
    }
  }
  __syncthreads();  // B3: C2P dead

  // ---- phase 3: stage K (zero-filled halo) and posq
  for (int idx = tid; idx < 384 * 8; idx += 1024) {
    int row = idx >> 3, c = idx & 7;
    int ks = n * BSZ - BSZ + row;
    uint4 v = make_uint4(0u, 0u, 0u, 0u);
    if (ks >= 0 && ks < SEQ) v = *(const uint4*)(kbh + (size_t)ks * HDIM + c * 8);
    *(uint4*)(smem + SM_K + row * 128 + ((c * 16) ^ ((row & 7) << 4))) = v;
  }
  for (int idx = tid; idx < 384 * 8; idx += 1024) {
    int row = idx >> 3, c = idx & 7;
    uint4 v = *(const uint4*)(pqh + row * HDIM + c * 8);
    *(uint4*)(smem + SM_PQ + row * 128 + ((c * 16) ^ ((row & 7) << 4))) = v;
  }
  __syncthreads();  // B4

  // ---- phase 4: p2c, 6 rounds of 2 k-subtiles (32 k each)
  unsigned short* Tl = (unsigned short*)(smem + SM_TL);
#pragma unroll
  for (int s2 = 0; s2 < 6; ++s2) {
    const int sa = 2 * s2, sb = 2 * s2 + 1;
    const int loa = iLUT[352 - 32 * sa];
    const int na = ((iLUT[510 - 32 * sa] - loa + 1) + 15) >> 4;
    const int lob = iLUT[352 - 32 * sb];
    const int nb = ((iLUT[510 - 32 * sb] - lob + 1) + 15) >> 4;
    const int jobsa = 2 * na;
    const int jobs = jobsa + 2 * nb;
    for (int tl_ = wave; tl_ < jobs; tl_ += 16) {
      int s, lo, j;
      if (tl_ < jobsa) { s = sa; lo = loa; j = tl_; }
      else             { s = sb; lo = lob; j = tl_ - jobsa; }
      int mt = j & 1, ntl = j >> 1;
      bf16x8 a0 = ldfrag(smem, SM_K, 32 * s + 16 * mt + l15, 128, 0, g);
      bf16x8 a1 = ldfrag(smem, SM_K, 32 * s + 16 * mt + l15, 128, 1, g);
      int prow = lo + 16 * ntl + l15;
      prow = prow > 383 ? 383 : prow;
      bf16x8 b0 = ldfrag(smem, SM_PQ, prow, 128, 0, g);
      bf16x8 b1 = ldfrag(smem, SM_PQ, prow, 128, 1, g);
      f32x4 c = {0.f, 0.f, 0.f, 0.f};
      c = MFMA16(a0, b0, c);
      c = MFMA16(a1, b1, c);
#pragma unroll
      for (int r = 0; r < 4; ++r)
        Tl[(s & 1) * 5888 + (16 * mt + 4 * g + r) * 184 + 16 * ntl + l15] =
            f2bf(c[r]);
    }
    __syncthreads();
    // gather: rounds 0-2 belong to kh=0 waves, 3-5 to kh=1 (static acc idx)
    if (kh == (s2 >= 3 ? 1 : 0)) {
      const int u = (s2 >= 3) ? (s2 - 3) : s2;   // compile-time per unroll
#pragma unroll
      for (int tt2 = 0; tt2 < 4; ++tt2) {
        const int ss = tt2 >> 1, tt = tt2 & 1;
        const int s = 2 * s2 + ss;
        const int lo = ss ? lob : loa;
#pragma unroll
        for (int r = 0; r < 4; ++r) {
          int k = 32 * s + 16 * tt + 4 * g + r;
          int idxv = iLUT[qg - k + 383];
          acc[4 * u + tt2][r] +=
              bf2f(Tl[(s & 1) * 5888 + (16 * tt + 4 * g + r) * 184 + idxv - lo]);
        }
      }
    }
    __syncthreads();
  }

  // ---- phase 5: QK^T accumulate (A = K rows of this wave's half, B = Q^T)
  __builtin_amdgcn_s_setprio(1);
#pragma unroll
  for (int t = 0; t < 12; ++t) {
    int krow = 192 * kh + 16 * t + l15;
    bf16x8 a0 = ldfrag(smem, SM_K, krow, 128, 0, g);
    bf16x8 a1 = ldfrag(smem, SM_K, krow, 128, 1, g);
    acc[t] = MFMA16(a0, qf0, acc[t]);
    acc[t] = MFMA16(a1, qf1, acc[t]);
  }
  __builtin_amdgcn_s_setprio(0);
  __syncthreads();  // B5: K, PQ, Tl dead

  // ---- phase 6: stage Vt (zero-filled halo) into PQ region
  for (int idx = tid; idx < 64 * 48; idx += 1024) {
    int row = idx / 48, c = idx - row * 48;
    int col0 = n * BSZ - BSZ + c * 8;
    uint4 v = make_uint4(0u, 0u, 0u, 0u);
    if (col0 >= 0 && col0 < SEQ)
      v = *(const uint4*)(vtbh + (size_t)row * SEQ + col0);
    *(uint4*)(smem + SM_VT + row * 768 + ((c * 16) ^ ((row & 7) << 4))) = v;
  }

  // ---- phase 7: softmax partial (this wave's k-half) + cross-pair merge
  float m = -1e30f;
#pragma unroll
  for (int t = 0; t < 12; ++t)
#pragma unroll
    for (int r = 0; r < 4; ++r) m = fmaxf(m, acc[t][r]);
  m = fmaxf(m, __shfl_xor(m, 16));
  m = fmaxf(m, __shfl_xor(m, 32));
  float sum = 0.f;
#pragma unroll
  for (int t = 0; t < 12; ++t)
#pragma unroll
    for (int r = 0; r < 4; ++r) {
      float p = exp2f((acc[t][r] - m) * SOFT_C);
      acc[t][r] = p;
      sum += p;
    }
  sum += __shfl_xor(sum, 16);
  sum += __shfl_xor(sum, 32);

  float* m_red = (float*)(smem + SM_RED);
  float* s_red = m_red + 256;
  if (lane < 16) {
    m_red[kh * 128 + qg] = m;
    s_red[kh * 128 + qg] = sum;
  }
  __syncthreads();  // B6: Vt + red ready

  float m_o = m_red[(1 - kh) * 128 + qg];
  float s_o = s_red[(1 - kh) * 128 + qg];
  float M = fmaxf(m, m_o);
  float e_own = exp2f((m - M) * SOFT_C);
  float denom = sum * e_own + s_o * exp2f((m_o - M) * SOFT_C);
  float mult = e_own / denom;

  bf16x8 pa[6];
#pragma unroll
  for (int kt = 0; kt < 6; ++kt) {
    union { bf16x8 v; unsigned short u[8]; } w;
#pragma unroll
    for (int j = 0; j < 4; ++j) w.u[j] = f2bf(acc[2 * kt][j] * mult);
#pragma unroll
    for (int j = 0; j < 4; ++j) w.u[4 + j] = f2bf(acc[2 * kt + 1][j] * mult);
    pa[kt] = w.v;
  }

  // ---- phase 8: PV partial over this wave's 6 k-32-slices; merge pairs
  f32x4 o[4];
  __builtin_amdgcn_s_setprio(1);
#pragma unroll
  for (int nt = 0; nt < 4; ++nt) {
    o[nt] = (f32x4){0.f, 0.f, 0.f, 0.f};
#pragma unroll
    for (int kt = 0; kt < 6; ++kt) {
      bf16x8 bv = ldfrag(smem, SM_VT, 16 * nt + l15, 768, 6 * kh + kt, g);
      o[nt] = MFMA16(pa[kt], bv, o[nt]);
    }
  }
  __builtin_amdgcn_s_setprio(0);

  float* O32 = (float*)(smem + SM_O32);
  if (kh == 0) {
#pragma unroll
    for (int nt = 0; nt < 4; ++nt)
#pragma unroll
      for (int r = 0; r < 4; ++r)
        O32[(qs + 4 * g + r) * 68 + 16 * nt + l15] = o[nt][r];
  }
  __syncthreads();  // B7

  if (kh == 1) {
    unsigned short* ctxg = ctx + ((size_t)b * SEQ + n * BSZ) * HID + h * HDIM;
#pragma unroll
    for (int nt = 0; nt < 4; ++nt)
#pragma unroll
      for (int r = 0; r < 4; ++r) {
        float v = o[nt][r] + O32[(qs + 4 * g + r) * 68 + 16 * nt + l15];
        ctxg[(size_t)(qs + 4 * g + r) * HID + 16 * nt + l15] = f2bf(v);
      }
  }
}

// ---------------------------------------------------------------------------
// Out projection bf16 MFMA + bias + residual -> fp32 out.
__global__ __launch_bounds__(256) void out_mfma(
    const unsigned short* __restrict__ ctx, const unsigned short* __restrict__ WoT,
    const float* __restrict__ bo, const float* __restrict__ hidden,
    float* __restrict__ out) {
  __shared__ unsigned short As[8192];
  __shared__ unsigned short Bs[8192];
  const int t = threadIdx.x;
  const int lane = t & 63;
  const int l15 = lane & 15, g = lane >> 4;
  const int wave = t >> 6;
  const int wy = wave >> 1, wx = wave & 1;
  const int n0 = blockIdx.x * 128;
  const int m0 = blockIdx.y * 128;

  f32x4 acc[4][4];
#pragma unroll
  for (int i = 0; i < 4; ++i)
#pragma unroll
    for (int j = 0; j < 4; ++j) acc[i][j] = (f32x4){0.f, 0.f, 0.f, 0.f};

  for (int k0 = 0; k0 < HID; k0 += 64) {
#pragma unroll
    for (int i = 0; i < 4; ++i) {
      int c = t + i * 256;
      int row = c >> 3, cx = c & 7;
      uint4 v = *(const uint4*)(ctx + (size_t)(m0 + row) * HID + k0 + cx * 8);
      *(uint4*)((char*)As + row * 128 + ((cx * 16) ^ ((row & 7) << 4))) = v;
    }
#pragma unroll
    for (int i = 0; i < 4; ++i) {
      int c = t + i * 256;
      int row = c >> 3, cx = c & 7;
      uint4 v = *(const uint4*)(WoT + (size_t)(n0 + row) * HID + k0 + cx * 8);
      *(uint4*)((char*)Bs + row * 128 + ((cx * 16) ^ ((row & 7) << 4))) = v;
    }
    __syncthreads();
    bf16x8 af[4][2], bf[4][2];
#pragma unroll
    for (int mt = 0; mt < 4; ++mt) {
      int row = wy * 64 + mt * 16 + l15;
      const char* p = (const char*)As + row * 128;
      int swz = (row & 7) << 4;
#pragma unroll
      for (int s = 0; s < 2; ++s)
        af[mt][s] = *(const bf16x8*)(p + ((s * 64 + g * 16) ^ swz));
    }
#pragma unroll
    for (int nt = 0; nt < 4; ++nt) {
      int row = wx * 64 + nt * 16 + l15;
      const char* p = (const char*)Bs + row * 128;
      int swz = (row & 7) << 4;
#pragma unroll
      for (int s = 0; s < 2; ++s)
        bf[nt][s] = *(const bf16x8*)(p + ((s * 64 + g * 16) ^ swz));
    }
#pragma unroll
    for (int mt = 0; mt < 4; ++mt)
#pragma unroll
      for (int nt = 0; nt < 4; ++nt) {
        acc[mt][nt] = MFMA16(af[mt][0], bf[nt][0], acc[mt][nt]);
        acc[mt][nt] = MFMA16(af[mt][1], bf[nt][1], acc[mt][nt]);
      }
    __syncthreads();
  }

#pragma unroll
  for (int nt = 0; nt < 4; ++nt) {
    int gn = n0 + wx * 64 + nt * 16 + l15;
    float bval = bo[gn];
#pragma unroll
    for (int mt = 0; mt < 4; ++mt) {
      f32x4 a = acc[mt][nt];
#pragma unroll
      for (int r = 0; r < 4; ++r) {
        int m = m0 + wy * 64 + mt * 16 + 4 * g + r;
        size_t off = (size_t)m * HID + gn;
        out[off] = a[r] + bval + hidden[off];
      }
    }
  }
}

// In-place LayerNorm over rows of 768.
__global__ __launch_bounds__(256) void ln_kernel(float* __restrict__ x,
                                                 const float* __restrict__ sc,
                                                 const float* __restrict__ bi) {
  __shared__ float red[8];
  int row = blockIdx.x;
  int t = threadIdx.x;
  float* xr = x + (size_t)row * HID;
  float e0 = xr[t], e1 = xr[t + 256], e2 = xr[t + 512];
  float ssum = e0 + e1 + e2;
#pragma unroll
  for (int o = 1; o < 64; o <<= 1) ssum += __shfl_xor(ssum, o);
  int w = t >> 6;
  if ((t & 63) == 0) red[w] = ssum;
  __syncthreads();
  float mu = (red[0] + red[1] + red[2] + red[3]) * (1.0f / 768.0f);
  float d0 = e0 - mu, d1 = e1 - mu, d2 = e2 - mu;
  float sq = d0 * d0 + d1 * d1 + d2 * d2;
#pragma unroll
  for (int o = 1; o < 64; o <<= 1) sq += __shfl_xor(sq, o);
  __syncthreads();
  if ((t & 63) == 0) red[4 + w] = sq;
  __syncthreads();
  float var = (red[4] + red[5] + red[6] + red[7]) * (1.0f / 768.0f);
  float rstd = 1.0f / sqrtf(var + 1e-7f);
  xr[t] = d0 * rstd * sc[t] + bi[t];
  xr[t + 256] = d1 * rstd * sc[t + 256] + bi[t + 256];
  xr[t + 512] = d2 * rstd * sc[t + 512] + bi[t + 512];
}

extern "C" void kernel_launch(void* const* d_in, const int* in_sizes, int n_in,
                              void* d_out, int out_size, void* d_ws,
                              size_t ws_size, hipStream_t stream) {
  (void)in_sizes; (void)n_in; (void)out_size; (void)ws_size;
  const float* hidden = (const float*)d_in[0];
  const float* relpos = (const float*)d_in[1];
  const float* Wq = (const float*)d_in[2];
  const float* bq = (const float*)d_in[3];
  const float* Wk = (const float*)d_in[4];
  const float* bk = (const float*)d_in[5];
  const float* Wv = (const float*)d_in[6];
  const float* bv = (const float*)d_in[7];
  const float* Wo = (const float*)d_in[8];
  const float* bo = (const float*)d_in[9];
  const float* lns = (const float*)d_in[10];
  const float* lnb = (const float*)d_in[11];
  float* out = (float*)d_out;

  // Workspace (ushort units): q | k | vt | ctx | posq | posk | WqkvT(=WoT)
  unsigned short* ws = (unsigned short*)d_ws;
  const size_t QE = (size_t)48 * SEQ * HDIM;  // 25,165,824
  unsigned short* qws = ws;
  unsigned short* kws = qws + QE;
  unsigned short* vt = kws + QE;
  unsigned short* ctx = vt + QE;
  unsigned short* posq = ctx + QE;
  unsigned short* posk = posq + (size_t)NHEADS * PBUCK * HDIM;
  unsigned short* WqkvT = posk + (size_t)NHEADS * PBUCK * HDIM;
  unsigned short* WoT = WqkvT;  // alias: WqkvT dead before conv of Wo

  static bool attrib_set = false;
  if (!attrib_set) {
    hipFuncSetAttribute((const void*)attn_kernel,
                        hipFuncAttributeMaxDynamicSharedMemorySize, SMEM_ATTN);
    attrib_set = true;
  }

  conv_wt<<<dim3(12, 12, 3), 256, 0, stream>>>(Wq, Wk, Wv, WqkvT);
  pos_gemm<<<dim3(8, 24), 256, 0, stream>>>(relpos, Wq, Wk, bq, bk, posq, posk);
  qkv_mfma<<<dim3(18, 256), 256, 0, stream>>>(hidden, WqkvT, bq, bk, bv, qws,
                                              kws, vt);
  conv_wt<<<dim3(12, 12, 1), 256, 0, stream>>>(Wo, Wo, Wo, WoT);
  attn_kernel<<<3072, 1024, SMEM_ATTN, stream>>>(qws, kws, vt, posq, posk, ctx);
  out_mfma<<<dim3(6, 256), 256, 0, stream>>>(ctx, WoT, bo, hidden, out);
  ln_kernel<<<32768, 256, 0, stream>>>(out, lns, lnb);
}

// Round 6
// 901.207 us; speedup vs baseline: 1.0003x; 1.0003x over previous
//
#include <hip/hip_runtime.h>
#include <math.h>

// ---------------------------------------------------------------------------
// LocalSlidingWindow_DisentangledAttention — Round 6: R5 16-wave split-k attn
// with the VGPR spill fixed: __launch_bounds__(1024,4) (128-reg cap, not 64)
// + lazy pa conversion in PV (peak regs ~100 < 128 -> no scratch).
// ---------------------------------------------------------------------------

#define NHEADS 12
#define HDIM   64
#define SEQ    8192
#define HID    768
#define BSZ    128
#define WIN    384
#define PBUCK  512

typedef __attribute__((ext_vector_type(8))) short bf16x8;
typedef __attribute__((ext_vector_type(4))) float f32x4;
#define MFMA16(a, b, c) __builtin_amdgcn_mfma_f32_16x16x32_bf16((a), (b), (c), 0, 0, 0)

// attn LDS byte map (dynamic, 151552 total)
#define SM_C2P 0        // [128][392] bf16 = 100352  (phase 1-2)
#define SM_K   0        // [384][64]  bf16 = 49152   (phase 4-5)
#define SM_O32 0        // [128][68]  f32  = 34816   (PV merge)
#define SM_PQ  49152    // [384][64]  bf16 = 49152   (phase 4)
#define SM_VT  49152    // [64][384]  bf16 = 49152   (PV)
#define SM_PKH 100352   // [384][64]  bf16 = 49152   (phase 1)
#define SM_TL  100352   // 2 x [32][184] bf16 = 23552 (phase 4)
#define SM_RED 124160   // m[256] + s[256] f32 = 2048 (softmax merge)
#define SM_LUT 149504   // [511] int = 2044
#define SMEM_ATTN 151552

#define SOFT_C 0.10411790f   // log2(e)/sqrt(192)

__device__ __forceinline__ unsigned short f2bf(float f) {
  unsigned int x = __builtin_bit_cast(unsigned int, f);
  unsigned int r = (x + 0x7FFFu + ((x >> 16) & 1u)) >> 16;
  return (unsigned short)r;
}
__device__ __forceinline__ float bf2f(unsigned short u) {
  unsigned int x = ((unsigned int)u) << 16;
  return __builtin_bit_cast(float, x);
}

// idx(rel) for rel in [-383, 127]
__device__ __forceinline__ int bucket_idx(int rel) {
  if (rel >= -128) return rel + 256;
  float a = (float)(-rel);
  float t = logf(a * (1.0f / 128.0f));
  t = t / 0.6892332813f;
  t = t * 127.0f;
  int lp = (int)(ceilf(t) + 128.0f);
  int r = 256 - lp;
  return r < 0 ? 0 : r;
}

// Fragment load from swizzled row-major bf16 LDS tile.
__device__ __forceinline__ bf16x8 ldfrag(const char* sm, int byteBase, int row,
                                         int rowBytes, int slice, int g) {
  const int swz = (row & 7) << 4;
  const char* p = sm + byteBase + row * rowBytes;
  union { bf16x8 v; uint2 u2[2]; } w;
  w.u2[0] = *(const uint2*)(p + (((slice << 6) + (g << 3)) ^ swz));
  w.u2[1] = *(const uint2*)(p + (((slice << 6) + 32 + (g << 3)) ^ swz));
  return w.v;
}

// ---------------------------------------------------------------------------
// Weight transpose fp32 -> bf16: Wt[z*768 + n][k] = W_z[k][n]
__global__ __launch_bounds__(256) void conv_wt(const float* __restrict__ W0,
                                               const float* __restrict__ W1,
                                               const float* __restrict__ W2,
                                               unsigned short* __restrict__ Wt) {
  __shared__ float tile[64][65];
  int bx = blockIdx.x, by = blockIdx.y, z = blockIdx.z;
  const float* W = (z == 0) ? W0 : (z == 1 ? W1 : W2);
  int t = threadIdx.x;
  int c = t & 63, r0 = (t >> 6) * 16;
#pragma unroll
  for (int rr = 0; rr < 16; ++rr)
    tile[r0 + rr][c] = W[(size_t)(by * 64 + r0 + rr) * HID + bx * 64 + c];
  __syncthreads();
#pragma unroll
  for (int rr = 0; rr < 16; ++rr) {
    int nw = r0 + rr;
    Wt[((size_t)z * HID + bx * 64 + nw) * HID + by * 64 + c] = f2bf(tile[c][nw]);
  }
}

// Positional projection (fp32 math) -> bf16 posq/posk [h][512][64]
__global__ __launch_bounds__(256) void pos_gemm(
    const float* __restrict__ relpos, const float* __restrict__ Wq,
    const float* __restrict__ Wk, const float* __restrict__ bq,
    const float* __restrict__ bk, unsigned short* __restrict__ posq,
    unsigned short* __restrict__ posk) {
  __shared__ float At[32][68];
  __shared__ float Bs[32][68];
  int m0 = blockIdx.x * 64;
  int n0 = blockIdx.y * 64;
  int w = n0 / HID;
  int nc0 = n0 % HID;
  const float* W = (w == 0) ? Wq : Wk;
  const float* bias = (w == 0) ? bq : bk;
  int t = threadIdx.x;
  int tx = t & 15, ty = t >> 4;
  float acc[4][4] = {};
  for (int k0 = 0; k0 < HID; k0 += 32) {
#pragma unroll
    for (int u = 0; u < 2; ++u) {
      int f = t * 2 + u;
      int r = f >> 3, c4 = f & 7;
      float4 av = *(const float4*)(relpos + (size_t)(m0 + r) * HID + k0 + c4 * 4);
      At[c4 * 4 + 0][r] = av.x; At[c4 * 4 + 1][r] = av.y;
      At[c4 * 4 + 2][r] = av.z; At[c4 * 4 + 3][r] = av.w;
    }
#pragma unroll
    for (int u = 0; u < 2; ++u) {
      int f = t * 2 + u;
      int kk = f >> 4, c4 = f & 15;
      float4 bv4 = *(const float4*)(W + (size_t)(k0 + kk) * HID + nc0 + c4 * 4);
      *(float4*)&Bs[kk][c4 * 4] = bv4;
    }
    __syncthreads();
#pragma unroll
    for (int kk = 0; kk < 32; ++kk) {
      float4 a4 = *(const float4*)&At[kk][ty * 4];
      float4 b4 = *(const float4*)&Bs[kk][tx * 4];
      float av[4] = {a4.x, a4.y, a4.z, a4.w};
      float bvv[4] = {b4.x, b4.y, b4.z, b4.w};
#pragma unroll
      for (int i = 0; i < 4; ++i)
#pragma unroll
        for (int jj = 0; jj < 4; ++jj) acc[i][jj] += av[i] * bvv[jj];
    }
    __syncthreads();
  }
  int h = nc0 >> 6;
  unsigned short* dst = (w == 0) ? posq : posk;
#pragma unroll
  for (int i = 0; i < 4; ++i) {
    int p = m0 + ty * 4 + i;
    ushort4 o;
    o.x = f2bf(acc[i][0] + bias[nc0 + tx * 4 + 0]);
    o.y = f2bf(acc[i][1] + bias[nc0 + tx * 4 + 1]);
    o.z = f2bf(acc[i][2] + bias[nc0 + tx * 4 + 2]);
    o.w = f2bf(acc[i][3] + bias[nc0 + tx * 4 + 3]);
    *(ushort4*)(dst + ((size_t)h * PBUCK + p) * HDIM + tx * 4) = o;
  }
}

// ---------------------------------------------------------------------------
// QKV projection, bf16 MFMA. Tile 128x128, BK=64, 256 thr = 4 waves (2x2).
__global__ __launch_bounds__(256) void qkv_mfma(
    const float* __restrict__ hidden, const unsigned short* __restrict__ Wt,
    const float* __restrict__ bq, const float* __restrict__ bk,
    const float* __restrict__ bv, unsigned short* __restrict__ qws,
    unsigned short* __restrict__ kws, unsigned short* __restrict__ vt) {
  __shared__ unsigned short As[8192];
  __shared__ unsigned short Bs[8192];
  const int t = threadIdx.x;
  const int lane = t & 63;
  const int l15 = lane & 15, g = lane >> 4;
  const int wave = t >> 6;
  const int wy = wave >> 1, wx = wave & 1;
  const int n0 = blockIdx.x * 128;
  const int m0 = blockIdx.y * 128;

  f32x4 acc[4][4];
#pragma unroll
  for (int i = 0; i < 4; ++i)
#pragma unroll
    for (int j = 0; j < 4; ++j) acc[i][j] = (f32x4){0.f, 0.f, 0.f, 0.f};

  for (int k0 = 0; k0 < HID; k0 += 64) {
#pragma unroll
    for (int i = 0; i < 4; ++i) {
      int c = t + i * 256;
      int row = c >> 3, cx = c & 7;
      const float4* src =
          (const float4*)(hidden + (size_t)(m0 + row) * HID + k0 + cx * 8);
      float4 a = src[0], b = src[1];
      union { bf16x8 v; unsigned short u[8]; } w;
      w.u[0] = f2bf(a.x); w.u[1] = f2bf(a.y); w.u[2] = f2bf(a.z); w.u[3] = f2bf(a.w);
      w.u[4] = f2bf(b.x); w.u[5] = f2bf(b.y); w.u[6] = f2bf(b.z); w.u[7] = f2bf(b.w);
      *(bf16x8*)((char*)As + row * 128 + ((cx * 16) ^ ((row & 7) << 4))) = w.v;
    }
#pragma unroll
    for (int i = 0; i < 4; ++i) {
      int c = t + i * 256;
      int row = c >> 3, cx = c & 7;
      uint4 v = *(const uint4*)(Wt + (size_t)(n0 + row) * HID + k0 + cx * 8);
      *(uint4*)((char*)Bs + row * 128 + ((cx * 16) ^ ((row & 7) << 4))) = v;
    }
    __syncthreads();
    bf16x8 af[4][2], bf[4][2];
#pragma unroll
    for (int mt = 0; mt < 4; ++mt) {
      int row = wy * 64 + mt * 16 + l15;
      const char* p = (const char*)As + row * 128;
      int swz = (row & 7) << 4;
#pragma unroll
      for (int s = 0; s < 2; ++s)
        af[mt][s] = *(const bf16x8*)(p + ((s * 64 + g * 16) ^ swz));
    }
#pragma unroll
    for (int nt = 0; nt < 4; ++nt) {
      int row = wx * 64 + nt * 16 + l15;
      const char* p = (const char*)Bs + row * 128;
      int swz = (row & 7) << 4;
#pragma unroll
      for (int s = 0; s < 2; ++s)
        bf[nt][s] = *(const bf16x8*)(p + ((s * 64 + g * 16) ^ swz));
    }
#pragma unroll
    for (int mt = 0; mt < 4; ++mt)
#pragma unroll
      for (int nt = 0; nt < 4; ++nt) {
        acc[mt][nt] = MFMA16(af[mt][0], bf[nt][0], acc[mt][nt]);
        acc[mt][nt] = MFMA16(af[mt][1], bf[nt][1], acc[mt][nt]);
      }
    __syncthreads();
  }

  const int w = n0 / HID;
  const float* bias = (w == 0) ? bq : (w == 1 ? bk : bv);
#pragma unroll
  for (int nt = 0; nt < 4; ++nt) {
    int gn = n0 + wx * 64 + nt * 16 + l15;
    int nc = gn - w * HID;
    int h = nc >> 6, d = nc & 63;
    float bval = bias[nc];
#pragma unroll
    for (int mt = 0; mt < 4; ++mt) {
      f32x4 a = acc[mt][nt];
#pragma unroll
      for (int r = 0; r < 4; ++r) {
        int m = m0 + wy * 64 + mt * 16 + 4 * g + r;
        int bl = m >> 13, s = m & 8191;
        size_t bh = (size_t)bl * NHEADS + h;
        unsigned short val = f2bf(a[r] + bval);
        if (w == 0)
          qws[(bh * SEQ + s) * HDIM + d] = val;
        else if (w == 1)
          kws[(bh * SEQ + s) * HDIM + d] = val;
        else
          vt[bh * ((size_t)HDIM * SEQ) + (size_t)d * SEQ + s] = val;
      }
    }
  }
}

// ---------------------------------------------------------------------------
// MFMA attention, 16 waves. wave = (qw = wave&7 -> q-strip, kh = wave>>3 ->
// k-half of 192). acc[12] f32x4: S[k = 192kh+16t+4g+r][q = 16qw+l15].
// launch_bounds(1024,4): VGPR cap 128 (NOT 64) -> no scratch spill.
__global__ __launch_bounds__(1024, 4) void attn_kernel(
    const unsigned short* __restrict__ qws, const unsigned short* __restrict__ kws,
    const unsigned short* __restrict__ vt, const unsigned short* __restrict__ posq,
    const unsigned short* __restrict__ posk, unsigned short* __restrict__ ctx) {
  extern __shared__ char smem[];
  int* iLUT = (int*)(smem + SM_LUT);

  const int tid = threadIdx.x;
  const int wave = tid >> 6;
  const int lane = tid & 63;
  const int l15 = lane & 15;
  const int g = lane >> 4;
  const int qw = wave & 7, kh = wave >> 3;
  const int qs = qw << 4;
  const int qg = qs + l15;           // this lane's softmax q row

  const int n = blockIdx.x & 63;
  const int bh = blockIdx.x >> 6;
  const int h = bh % NHEADS;
  const int b = bh / NHEADS;

  const unsigned short* kbh = kws + (size_t)bh * SEQ * HDIM;
  const unsigned short* vtbh = vt + (size_t)bh * ((size_t)HDIM * SEQ);
  const unsigned short* pqh = posq + (size_t)h * PBUCK * HDIM;
  const unsigned short* pkh = posk + (size_t)h * PBUCK * HDIM;

  // ---- phase 0: stage full posk [384][64], LUT; load Q fragments from global
  for (int idx = tid; idx < 384 * 8; idx += 1024) {
    int row = idx >> 3, c = idx & 7;
    uint4 v = *(const uint4*)(pkh + row * HDIM + c * 8);
    *(uint4*)(smem + SM_PKH + row * 128 + ((c * 16) ^ ((row & 7) << 4))) = v;
  }
  if (tid < 511) iLUT[tid] = bucket_idx(tid - 383);

  bf16x8 qf0, qf1;
  {
    const char* qrow =
        (const char*)(qws + ((size_t)bh * SEQ + n * BSZ + qs + l15) * HDIM);
    union { bf16x8 v; uint2 u2[2]; } u0, u1;
    u0.u2[0] = *(const uint2*)(qrow + g * 8);
    u0.u2[1] = *(const uint2*)(qrow + g * 8 + 32);
    u1.u2[0] = *(const uint2*)(qrow + 64 + g * 8);
    u1.u2[1] = *(const uint2*)(qrow + 96 + g * 8);
    qf0 = u0.v; qf1 = u1.v;
  }
  __syncthreads();  // B1

  // ---- phase 1: C2P[q][p] = Q . posk^T ; wave does q-strip qw x p-half kh
  unsigned short* C2P = (unsigned short*)(smem + SM_C2P);
  __builtin_amdgcn_s_setprio(1);
#pragma unroll
  for (int ntl = 0; ntl < 12; ++ntl) {
    int prow = 192 * kh + 16 * ntl + l15;
    bf16x8 b0 = ldfrag(smem, SM_PKH, prow, 128, 0, g);
    bf16x8 b1 = ldfrag(smem, SM_PKH, prow, 128, 1, g);
    f32x4 c = {0.f, 0.f, 0.f, 0.f};
    c = MFMA16(qf0, b0, c);
    c = MFMA16(qf1, b1, c);
#pragma unroll
    for (int r = 0; r < 4; ++r)
      C2P[(qs + 4 * g + r) * 392 + prow] = f2bf(c[r]);
  }
  __builtin_amdgcn_s_setprio(0);
  __syncthreads();  // B2

  // ---- phase 2: gather c2p into acc
  f32x4 acc[12];
#pragma unroll
  for (int t = 0; t < 12; ++t) acc[t] = (f32x4){0.f, 0.f, 0.f, 0.f};
  {
    const unsigned short* c2pRow = C2P + qg * 392;
#pragma unroll
    for (int t = 0; t < 12; ++t) {
#pragma unroll
      for (int r = 0; r < 4; ++r) {
        int k = 192 * kh + 16 * t + 4 * g + r;
        int idxv = iLUT[qg - k + 383];
        acc[t][r] += bf2f(c2pRow[idxv]);
      }
    }
  }
  __syncthreads();  // B3: C2P dead

  // ---- phase 3: stage K (zero-filled halo) and posq
  for (int idx = tid; idx < 384 * 8; idx += 1024) {
    int row = idx >> 3, c = idx & 7;
    int ks = n * BSZ - BSZ + row;
    uint4 v = make_uint4(0u, 0u, 0u, 0u);
    if (ks >= 0 && ks < SEQ) v = *(const uint4*)(kbh + (size_t)ks * HDIM + c * 8);
    *(uint4*)(smem + SM_K + row * 128 + ((c * 16) ^ ((row & 7) << 4))) = v;
  }
  for (int idx = tid; idx < 384 * 8; idx += 1024) {
    int row = idx >> 3, c = idx & 7;
    uint4 v = *(const uint4*)(pqh + row * HDIM + c * 8);
    *(uint4*)(smem + SM_PQ + row * 128 + ((c * 16) ^ ((row & 7) << 4))) = v;
  }
  __syncthreads();  // B4

  // ---- phase 4: p2c, 6 rounds of 2 k-subtiles (32 k each)
  unsigned short* Tl = (unsigned short*)(smem + SM_TL);
#pragma unroll
  for (int s2 = 0; s2 < 6; ++s2) {
    const int sa = 2 * s2, sb = 2 * s2 + 1;
    const int loa = iLUT[352 - 32 * sa];
    const int na = ((iLUT[510 - 32 * sa] - loa + 1) + 15) >> 4;
    const int lob = iLUT[352 - 32 * sb];
    const int nb = ((iLUT[510 - 32 * sb] - lob + 1) + 15) >> 4;
    const int jobsa = 2 * na;
    const int jobs = jobsa + 2 * nb;
    for (int tl_ = wave; tl_ < jobs; tl_ += 16) {
      int s, lo, j;
      if (tl_ < jobsa) { s = sa; lo = loa; j = tl_; }
      else             { s = sb; lo = lob; j = tl_ - jobsa; }
      int mt = j & 1, ntl = j >> 1;
      bf16x8 a0 = ldfrag(smem, SM_K, 32 * s + 16 * mt + l15, 128, 0, g);
      bf16x8 a1 = ldfrag(smem, SM_K, 32 * s + 16 * mt + l15, 128, 1, g);
      int prow = lo + 16 * ntl + l15;
      prow = prow > 383 ? 383 : prow;
      bf16x8 b0 = ldfrag(smem, SM_PQ, prow, 128, 0, g);
      bf16x8 b1 = ldfrag(smem, SM_PQ, prow, 128, 1, g);
      f32x4 c = {0.f, 0.f, 0.f, 0.f};
      c = MFMA16(a0, b0, c);
      c = MFMA16(a1, b1, c);
#pragma unroll
      for (int r = 0; r < 4; ++r)
        Tl[(s & 1) * 5888 + (16 * mt + 4 * g + r) * 184 + 16 * ntl + l15] =
            f2bf(c[r]);
    }
    __syncthreads();
    // gather: rounds 0-2 belong to kh=0 waves, 3-5 to kh=1 (static acc idx)
    if (kh == (s2 >= 3 ? 1 : 0)) {
      const int u = (s2 >= 3) ? (s2 - 3) : s2;   // compile-time per unroll
#pragma unroll
      for (int tt2 = 0; tt2 < 4; ++tt2) {
        const int ss = tt2 >> 1, tt = tt2 & 1;
        const int s = 2 * s2 + ss;
        const int lo = ss ? lob : loa;
#pragma unroll
        for (int r = 0; r < 4; ++r) {
          int k = 32 * s + 16 * tt + 4 * g + r;
          int idxv = iLUT[qg - k + 383];
          acc[4 * u + tt2][r] +=
              bf2f(Tl[(s & 1) * 5888 + (16 * tt + 4 * g + r) * 184 + idxv - lo]);
        }
      }
    }
    __syncthreads();
  }

  // ---- phase 5: QK^T accumulate (A = K rows of this wave's half, B = Q^T)
  __builtin_amdgcn_s_setprio(1);
#pragma unroll
  for (int t = 0; t < 12; ++t) {
    int krow = 192 * kh + 16 * t + l15;
    bf16x8 a0 = ldfrag(smem, SM_K, krow, 128, 0, g);
    bf16x8 a1 = ldfrag(smem, SM_K, krow, 128, 1, g);
    acc[t] = MFMA16(a0, qf0, acc[t]);
    acc[t] = MFMA16(a1, qf1, acc[t]);
  }
  __builtin_amdgcn_s_setprio(0);
  __syncthreads();  // B5: K, PQ, Tl dead

  // ---- phase 6: stage Vt (zero-filled halo) into PQ region
  for (int idx = tid; idx < 64 * 48; idx += 1024) {
    int row = idx / 48, c = idx - row * 48;
    int col0 = n * BSZ - BSZ + c * 8;
    uint4 v = make_uint4(0u, 0u, 0u, 0u);
    if (col0 >= 0 && col0 < SEQ)
      v = *(const uint4*)(vtbh + (size_t)row * SEQ + col0);
    *(uint4*)(smem + SM_VT + row * 768 + ((c * 16) ^ ((row & 7) << 4))) = v;
  }

  // ---- phase 7: softmax partial (this wave's k-half) + cross-pair merge
  float m = -1e30f;
#pragma unroll
  for (int t = 0; t < 12; ++t)
#pragma unroll
    for (int r = 0; r < 4; ++r) m = fmaxf(m, acc[t][r]);
  m = fmaxf(m, __shfl_xor(m, 16));
  m = fmaxf(m, __shfl_xor(m, 32));
  float sum = 0.f;
#pragma unroll
  for (int t = 0; t < 12; ++t)
#pragma unroll
    for (int r = 0; r < 4; ++r) {
      float p = exp2f((acc[t][r] - m) * SOFT_C);
      acc[t][r] = p;
      sum += p;
    }
  sum += __shfl_xor(sum, 16);
  sum += __shfl_xor(sum, 32);

  float* m_red = (float*)(smem + SM_RED);
  float* s_red = m_red + 256;
  if (lane < 16) {
    m_red[kh * 128 + qg] = m;
    s_red[kh * 128 + qg] = sum;
  }
  __syncthreads();  // B6: Vt + red ready

  float m_o = m_red[(1 - kh) * 128 + qg];
  float s_o = s_red[(1 - kh) * 128 + qg];
  float M = fmaxf(m, m_o);
  float e_own = exp2f((m - M) * SOFT_C);
  float denom = sum * e_own + s_o * exp2f((m_o - M) * SOFT_C);
  float mult = e_own / denom;

  // ---- phase 8: PV partial, kt-outer with LAZY pa conversion (1 live pa)
  f32x4 o[4];
#pragma unroll
  for (int nt = 0; nt < 4; ++nt) o[nt] = (f32x4){0.f, 0.f, 0.f, 0.f};
  __builtin_amdgcn_s_setprio(1);
#pragma unroll
  for (int kt = 0; kt < 6; ++kt) {
    union { bf16x8 v; unsigned short u[8]; } w;
#pragma unroll
    for (int j = 0; j < 4; ++j) w.u[j] = f2bf(acc[2 * kt][j] * mult);
#pragma unroll
    for (int j = 0; j < 4; ++j) w.u[4 + j] = f2bf(acc[2 * kt + 1][j] * mult);
#pragma unroll
    for (int nt = 0; nt < 4; ++nt) {
      bf16x8 bv = ldfrag(smem, SM_VT, 16 * nt + l15, 768, 6 * kh + kt, g);
      o[nt] = MFMA16(w.v, bv, o[nt]);
    }
  }
  __builtin_amdgcn_s_setprio(0);

  float* O32 = (float*)(smem + SM_O32);
  if (kh == 0) {
#pragma unroll
    for (int nt = 0; nt < 4; ++nt)
#pragma unroll
      for (int r = 0; r < 4; ++r)
        O32[(qs + 4 * g + r) * 68 + 16 * nt + l15] = o[nt][r];
  }
  __syncthreads();  // B7

  if (kh == 1) {
    unsigned short* ctxg = ctx + ((size_t)b * SEQ + n * BSZ) * HID + h * HDIM;
#pragma unroll
    for (int nt = 0; nt < 4; ++nt)
#pragma unroll
      for (int r = 0; r < 4; ++r) {
        float v = o[nt][r] + O32[(qs + 4 * g + r) * 68 + 16 * nt + l15];
        ctxg[(size_t)(qs + 4 * g + r) * HID + 16 * nt + l15] = f2bf(v);
      }
  }
}

// ---------------------------------------------------------------------------
// Out projection bf16 MFMA + bias + residual -> fp32 out.
__global__ __launch_bounds__(256) void out_mfma(
    const unsigned short* __restrict__ ctx, const unsigned short* __restrict__ WoT,
    const float* __restrict__ bo, const float* __restrict__ hidden,
    float* __restrict__ out) {
  __shared__ unsigned short As[8192];
  __shared__ unsigned short Bs[8192];
  const int t = threadIdx.x;
  const int lane = t & 63;
  const int l15 = lane & 15, g = lane >> 4;
  const int wave = t >> 6;
  const int wy = wave >> 1, wx = wave & 1;
  const int n0 = blockIdx.x * 128;
  const int m0 = blockIdx.y * 128;

  f32x4 acc[4][4];
#pragma unroll
  for (int i = 0; i < 4; ++i)
#pragma unroll
    for (int j = 0; j < 4; ++j) acc[i][j] = (f32x4){0.f, 0.f, 0.f, 0.f};

  for (int k0 = 0; k0 < HID; k0 += 64) {
#pragma unroll
    for (int i = 0; i < 4; ++i) {
      int c = t + i * 256;
      int row = c >> 3, cx = c & 7;
      uint4 v = *(const uint4*)(ctx + (size_t)(m0 + row) * HID + k0 + cx * 8);
      *(uint4*)((char*)As + row * 128 + ((cx * 16) ^ ((row & 7) << 4))) = v;
    }
#pragma unroll
    for (int i = 0; i < 4; ++i) {
      int c = t + i * 256;
      int row = c >> 3, cx = c & 7;
      uint4 v = *(const uint4*)(WoT + (size_t)(n0 + row) * HID + k0 + cx * 8);
      *(uint4*)((char*)Bs + row * 128 + ((cx * 16) ^ ((row & 7) << 4))) = v;
    }
    __syncthreads();
    bf16x8 af[4][2], bf[4][2];
#pragma unroll
    for (int mt = 0; mt < 4; ++mt) {
      int row = wy * 64 + mt * 16 + l15;
      const char* p = (const char*)As + row * 128;
      int swz = (row & 7) << 4;
#pragma unroll
      for (int s = 0; s < 2; ++s)
        af[mt][s] = *(const bf16x8*)(p + ((s * 64 + g * 16) ^ swz));
    }
#pragma unroll
    for (int nt = 0; nt < 4; ++nt) {
      int row = wx * 64 + nt * 16 + l15;
      const char* p = (const char*)Bs + row * 128;
      int swz = (row & 7) << 4;
#pragma unroll
      for (int s = 0; s < 2; ++s)
        bf[nt][s] = *(const bf16x8*)(p + ((s * 64 + g * 16) ^ swz));
    }
#pragma unroll
    for (int mt = 0; mt < 4; ++mt)
#pragma unroll
      for (int nt = 0; nt < 4; ++nt) {
        acc[mt][nt] = MFMA16(af[mt][0], bf[nt][0], acc[mt][nt]);
        acc[mt][nt] = MFMA16(af[mt][1], bf[nt][1], acc[mt][nt]);
      }
    __syncthreads();
  }

#pragma unroll
  for (int nt = 0; nt < 4; ++nt) {
    int gn = n0 + wx * 64 + nt * 16 + l15;
    float bval = bo[gn];
#pragma unroll
    for (int mt = 0; mt < 4; ++mt) {
      f32x4 a = acc[mt][nt];
#pragma unroll
      for (int r = 0; r < 4; ++r) {
        int m = m0 + wy * 64 + mt * 16 + 4 * g + r;
        size_t off = (size_t)m * HID + gn;
        out[off] = a[r] + bval + hidden[off];
      }
    }
  }
}

// In-place LayerNorm over rows of 768.
__global__ __launch_bounds__(256) void ln_kernel(float* __restrict__ x,
                                                 const float* __restrict__ sc,
                                                 const float* __restrict__ bi) {
  __shared__ float red[8];
  int row = blockIdx.x;
  int t = threadIdx.x;
  float* xr = x + (size_t)row * HID;
  float e0 = xr[t], e1 = xr[t + 256], e2 = xr[t + 512];
  float ssum = e0 + e1 + e2;
#pragma unroll
  for (int o = 1; o < 64; o <<= 1) ssum += __shfl_xor(ssum, o);
  int w = t >> 6;
  if ((t & 63) == 0) red[w] = ssum;
  __syncthreads();
  float mu = (red[0] + red[1] + red[2] + red[3]) * (1.0f / 768.0f);
  float d0 = e0 - mu, d1 = e1 - mu, d2 = e2 - mu;
  float sq = d0 * d0 + d1 * d1 + d2 * d2;
#pragma unroll
  for (int o = 1; o < 64; o <<= 1) sq += __shfl_xor(sq, o);
  __syncthreads();
  if ((t & 63) == 0) red[4 + w] = sq;
  __syncthreads();
  float var = (red[4] + red[5] + red[6] + red[7]) * (1.0f / 768.0f);
  float rstd = 1.0f / sqrtf(var + 1e-7f);
  xr[t] = d0 * rstd * sc[t] + bi[t];
  xr[t + 256] = d1 * rstd * sc[t + 256] + bi[t + 256];
  xr[t + 512] = d2 * rstd * sc[t + 512] + bi[t + 512];
}

extern "C" void kernel_launch(void* const* d_in, const int* in_sizes, int n_in,
                              void* d_out, int out_size, void* d_ws,
                              size_t ws_size, hipStream_t stream) {
  (void)in_sizes; (void)n_in; (void)out_size; (void)ws_size;
  const float* hidden = (const float*)d_in[0];
  const float* relpos = (const float*)d_in[1];
  const float* Wq = (const float*)d_in[2];
  const float* bq = (const float*)d_in[3];
  const float* Wk = (const float*)d_in[4];
  const float* bk = (const float*)d_in[5];
  const float* Wv = (const float*)d_in[6];
  const float* bv = (const float*)d_in[7];
  const float* Wo = (const float*)d_in[8];
  const float* bo = (const float*)d_in[9];
  const float* lns = (const float*)d_in[10];
  const float* lnb = (const float*)d_in[11];
  float* out = (float*)d_out;

  // Workspace (ushort units): q | k | vt | ctx | posq | posk | WqkvT(=WoT)
  unsigned short* ws = (unsigned short*)d_ws;
  const size_t QE = (size_t)48 * SEQ * HDIM;  // 25,165,824
  unsigned short* qws = ws;
  unsigned short* kws = qws + QE;
  unsigned short* vt = kws + QE;
  unsigned short* ctx = vt + QE;
  unsigned short* posq = ctx + QE;
  unsigned short* posk = posq + (size_t)NHEADS * PBUCK * HDIM;
  unsigned short* WqkvT = posk + (size_t)NHEADS * PBUCK * HDIM;
  unsigned short* WoT = WqkvT;  // alias: WqkvT dead before conv of Wo

  static bool attrib_set = false;
  if (!attrib_set) {
    hipFuncSetAttribute((const void*)attn_kernel,
                        hipFuncAttributeMaxDynamicSharedMemorySize, SMEM_ATTN);
    attrib_set = true;
  }

  conv_wt<<<dim3(12, 12, 3), 256, 0, stream>>>(Wq, Wk, Wv, WqkvT);
  pos_gemm<<<dim3(8, 24), 256, 0, stream>>>(relpos, Wq, Wk, bq, bk, posq, posk);
  qkv_mfma<<<dim3(18, 256), 256, 0, stream>>>(hidden, WqkvT, bq, bk, bv, qws,
                                              kws, vt);
  conv_wt<<<dim3(12, 12, 1), 256, 0, stream>>>(Wo, Wo, Wo, WoT);
  attn_kernel<<<3072, 1024, SMEM_ATTN, stream>>>(qws, kws, vt, posq, posk, ctx);
  out_mfma<<<dim3(6, 256), 256, 0, stream>>>(ctx, WoT, bo, hidden, out);
  ln_kernel<<<32768, 256, 0, stream>>>(out, lns, lnb);
}